// Round 8
// baseline (151.543 us; speedup 1.0000x reference)
//
#include <hip/hip_runtime.h>

// DispNetC correlation volume: out[b,d,h,w] = mean_c L[b,c,h,w]*R[b,c,h,w-d]
// for w>=d, else 0.  f32 in / f32 out.
//
// R7 post-mortem: load->pack register chains kept only ~2 loads/wave in
// flight (HBM 1.5 TB/s at 900cyc latency => ~8 loads/CU outstanding).
// Fix: hoist ALL 64 staging loads into registers first (64 in flight/wave),
// THEN pack to bf16 and write LDS. Everything else is the R7 structure
// (4 c-teams x 64ch, one-shot staging, band MFMA, LDS reduce).

typedef __attribute__((ext_vector_type(8))) short short8;   // MFMA A/B frag
typedef __attribute__((ext_vector_type(4))) float floatx4;  // MFMA C/D frag

#define NB 8
#define NC 256
#define NH 64
#define NWD 128
#define ND 40
#define KC 64                            // channels per team
#define TEAM_BYTES (2 * NWD * KC * 2)    // Ls+Rs (bf16) = 32 KB per team

__global__ __launch_bounds__(1024, 4) void corr_mfma5(
    const float* __restrict__ Lg,
    const float* __restrict__ Rg,
    float* __restrict__ out)
{
  __shared__ __align__(16) unsigned char smem[4 * TEAM_BYTES];  // 128 KB

  const int blk  = blockIdx.x;
  const int b    = blk >> 6;      // NH = 64
  const int h    = blk & 63;
  const int tid  = threadIdx.x;
  const int team = tid >> 8;      // 0..3: which 64-channel quarter
  const int ttid = tid & 255;
  const int lane = tid & 63;
  const int wavt = (tid >> 6) & 3;  // wave within team
  const int m    = lane & 15;
  const int q    = lane >> 4;

  unsigned short* Ls = (unsigned short*)(smem + team * TEAM_BYTES);
  unsigned short* Rs = Ls + NWD * KC;

  const int ws = ttid & 127;       // lane -> w (coalesced, 256B/wave-instr)
  const int ch = ttid >> 7;        // which 8-c slot within each 16-c group
  const size_t HW   = (size_t)NH * NWD;
  const size_t goff = (size_t)b * NC * HW + (size_t)h * NWD
                    + (size_t)(team * KC) * HW + ws;

  // ---- phase 1: issue ALL 64 loads (32 L + 32 R), no dependent math ----
  float lf[32], rf[32];
  #pragma unroll
  for (int it = 0; it < 4; ++it) {
    const size_t g = goff + (size_t)(it * 16 + ch * 8) * HW;
    #pragma unroll
    for (int p = 0; p < 8; ++p) {
      lf[it * 8 + p] = Lg[g + (size_t)p * HW];
      rf[it * 8 + p] = Rg[g + (size_t)p * HW];
    }
  }

  // ---- phase 2: round-half-up to bf16, pack pairs, write LDS ----
  // [w][c] layout, XOR-swizzled 8-c groups (verified 0-conflict in R6).
  #pragma unroll
  for (int it = 0; it < 4; ++it) {
    unsigned int lv[4], rv[4];
    #pragma unroll
    for (int p = 0; p < 4; ++p) {
      const unsigned int a0 = __float_as_uint(lf[it * 8 + 2 * p])     + 0x8000u;
      const unsigned int a1 = __float_as_uint(lf[it * 8 + 2 * p + 1]) + 0x8000u;
      lv[p] = (a0 >> 16) | (a1 & 0xFFFF0000u);
      const unsigned int b0 = __float_as_uint(rf[it * 8 + 2 * p])     + 0x8000u;
      const unsigned int b1 = __float_as_uint(rf[it * 8 + 2 * p + 1]) + 0x8000u;
      rv[p] = (b0 >> 16) | (b1 & 0xFFFF0000u);
    }
    const int grp = it * 2 + ch;                        // 8-c group, 0..7
    const int pos = ws * KC + ((grp ^ (ws & 7)) << 3);  // XOR swizzle
    *(uint4*)(&Ls[pos]) = make_uint4(lv[0], lv[1], lv[2], lv[3]);
    *(uint4*)(&Rs[pos]) = make_uint4(rv[0], rv[1], rv[2], rv[3]);
  }
  __syncthreads();

  // ---- band tiles (i, j=i+k), k=0..3; 26 tiles round-robined over 4 waves ----
  floatx4 acc[7];
  #pragma unroll
  for (int t = 0; t < 7; ++t) acc[t] = (floatx4){0.f, 0.f, 0.f, 0.f};
  #pragma unroll
  for (int ks = 0; ks < 2; ++ks) {       // two K=32 steps over the 64 channels
    #pragma unroll
    for (int tile = 0; tile < 26; ++tile) {
      if ((tile & 3) != wavt) continue;
      const int i  = (tile < 8) ? tile : (tile < 15) ? tile - 8
                   : (tile < 21) ? tile - 15 : tile - 21;
      const int k  = (tile < 8) ? 0 : (tile < 15) ? 1 : (tile < 21) ? 2 : 3;
      const int j  = i + k;
      const int tt = tile >> 2;
      const int ra = 16 * i + m;         // w' row for A (from R)
      const int rb = 16 * j + m;         // w  col for B (from L)
      const int grp = ks * 4 + q;        // lane reads c = 32*ks + 8*q + [0..7]
      const short8 av = *(const short8*)(&Rs[ra * KC + ((grp ^ (ra & 7)) << 3)]);
      const short8 bv = *(const short8*)(&Ls[rb * KC + ((grp ^ (rb & 7)) << 3)]);
      acc[tt] = __builtin_amdgcn_mfma_f32_16x16x32_bf16(av, bv, acc[tt], 0, 0, 0);
    }
  }
  __syncthreads();  // all teams done reading staged LDS

  // ---- dump partial tiles (f32) into own team's region ----
  float* P = (float*)(smem + team * TEAM_BYTES);
  #pragma unroll
  for (int tile = 0; tile < 26; ++tile) {
    if ((tile & 3) != wavt) continue;
    const int tt = tile >> 2;
    #pragma unroll
    for (int r = 0; r < 4; ++r)
      P[tile * 256 + (q * 4 + r) * 16 + m] = acc[tt][r];
  }
  __syncthreads();

  // ---- reduce the 4 team partials and store (also zero-fills w<d) ----
  for (int t = tid; t < ND * NWD; t += 1024) {
    const int d = t >> 7;
    const int w = t & 127;
    float v = 0.0f;
    if (w >= d) {
      const int wp  = w - d;
      const int i   = wp >> 4;
      const int k   = (w >> 4) - i;
      const int off = (k == 0) ? 0 : (k == 1) ? 8 : (k == 2) ? 15 : 21;
      const int idx = (off + i) * 256 + (wp & 15) * 16 + (w & 15);
      v = (((const float*)(smem + 0 * TEAM_BYTES))[idx] +
           ((const float*)(smem + 1 * TEAM_BYTES))[idx]) +
          (((const float*)(smem + 2 * TEAM_BYTES))[idx] +
           ((const float*)(smem + 3 * TEAM_BYTES))[idx]);
      v *= 0.00390625f;  // /256 (mean over C)
    }
    out[(((size_t)b * ND + d) * NH + h) * NWD + w] = v;
  }
}

extern "C" void kernel_launch(void* const* d_in, const int* in_sizes, int n_in,
                              void* d_out, int out_size, void* d_ws, size_t ws_size,
                              hipStream_t stream) {
  corr_mfma5<<<dim3(NB * NH), dim3(1024), 0, stream>>>(
      (const float*)d_in[0], (const float*)d_in[1], (float*)d_out);
}